// Round 20
// baseline (139.369 us; speedup 1.0000x reference)
//
#include <hip/hip_runtime.h>
#include <hip/hip_fp16.h>
#include <cstdint>

#define IN_F   4096
#define OUT_F  4096
#define BS     64      // sparsity block size
#define NB     64      // blocks per weight dim
#define N_TOK  8192
#define TM     256     // token tile per workgroup (4 waves x 64 rows)
#define NMT    (N_TOK / TM)   // 32 token tiles

// xt tile stride: 32 KB payload + 1 KB pad = 33 KB (non-power-of-2 to spread
// the convert's strided tile writes across HBM channels).
#define XT_STRIDE_B    33792ull
#define XT_STRIDE_U16  16896

typedef __attribute__((ext_vector_type(8))) _Float16       f16x8;
typedef __attribute__((ext_vector_type(8))) unsigned short u16x8;
typedef __attribute__((ext_vector_type(4))) unsigned short u16x4;
typedef __attribute__((ext_vector_type(4))) float          f32x4;

// ---------------- workspace layout (bytes) ----------------
// xt only: 2048 tiles (mt,kb) x 33 KB stride (u16[256][64] payload, swizzled).
// W is converted INSIDE the GEMM (no wt buffer -> no cross-XCD wt visibility).
#define WS_XT_OFF      0ull
#define WS_XT_BYTES    (2048ull * XT_STRIDE_B)         // ~69.2 MB
#define WS_NEEDED      WS_XT_BYTES

// wave-uniform ballot of the block-constant mask row `br`
__device__ __forceinline__ unsigned long long mask_ballot(
        const float* __restrict__ mask, int br, int lane) {
    float mv = mask[(size_t)(br * BS) * IN_F + (size_t)lane * BS];
    return __ballot(mv != 0.0f);
}

// pack 8 fp32 -> 8 fp16 (RNE) bit patterns
__device__ __forceinline__ u16x8 pack8(f32x4 a, f32x4 b) {
    u16x8 o;
#pragma unroll
    for (int j = 0; j < 4; ++j) o[j]     = __half_as_ushort(__float2half_rn(a[j]));
#pragma unroll
    for (int j = 0; j < 4; ++j) o[4 + j] = __half_as_ushort(__float2half_rn(b[j]));
    return o;
}

// ---------------------------------------------------------------------------
// Kernel 1: x -> packed swizzled xt tiles via LDS transpose (X only).
// XCD-affine: WG b handles mt = (b&7)*4 + ((b>>3)&3) so tiles are produced
// on the consuming XCD (producer L2 = consumer L2). rb = b>>5.
// Per 1024-col chunk: (1) batched 4KB-contiguous wave reads, cvt fp16 +
// XOR-swizzle into 16KB LDS; (2) 1KB-per-tile writes at the PADDED 33KB
// stride (channel-spread; unpadded 32KB measured 100us / 1.4TB/s in r15).
// ---------------------------------------------------------------------------
__global__ __launch_bounds__(256, 2)
void convert_x_kernel(const float* __restrict__ x,
                      unsigned short* __restrict__ xt) {
    __shared__ unsigned short tlds[16][8][64];   // 16 KB
    const int b   = blockIdx.x;                  // 0..1023
    const int xcd = b & 7;
    const int mt  = xcd * 4 + ((b >> 3) & 3);    // consumer-XCD affine
    const int rb  = b >> 5;                      // 8-row block 0..31
    const int t   = threadIdx.x;
    const size_t xrow0 = (size_t)(mt * TM + rb * 8) * IN_F;
    unsigned short* tb = xt + (size_t)(mt * 64) * XT_STRIDE_U16;

    const int kb_l = t >> 4;                     // 0..15 (phase-1 store)
    const int c4k  = t & 15;
    const int slot = c4k >> 1, h0 = (c4k & 1) * 4;

    for (int j = 0; j < 4; ++j) {                // 4 x 1024-col chunks
        // ---- phase 1: batched 4KB-contiguous reads, cvt + swizzled LDS ----
        f32x4 v[8];
#pragma unroll
        for (int l = 0; l < 8; ++l)              // row l: 4KB/WG contiguous
            v[l] = *(const f32x4*)(x + xrow0 + (size_t)l * IN_F
                                   + j * 1024 + t * 4);
#pragma unroll
        for (int l = 0; l < 8; ++l) {
            u16x4 o;
#pragma unroll
            for (int k2 = 0; k2 < 4; ++k2)
                o[k2] = __half_as_ushort(__float2half_rn(v[l][k2]));
            *(u16x4*)&tlds[kb_l][l][((slot ^ l) << 3) + h0] = o;
        }
        __syncthreads();
        // ---- phase 2: 1KB-per-tile writes at padded 33KB stride ----
#pragma unroll
        for (int l = 0; l < 4; ++l) {
            int wid = l * 256 + t;               // 0..1023
            int kk = wid >> 6, e = wid & 63;
            int row = e >> 3, s8 = e & 7;
            u16x8 vv = *(const u16x8*)&tlds[kk][row][s8 * 8];
            unsigned short* tile = tb + (size_t)(j * 16 + kk) * XT_STRIDE_U16;
            *(u16x8*)&tile[(rb * 8 + row) * 64 + s8 * 8] = vv;
        }
        __syncthreads();
    }
}

// async global->LDS, 16B per lane, contiguous 1KB per wave-instruction.
__device__ __forceinline__ void gll16(const void* g, void* l) {
    __builtin_amdgcn_global_load_lds(
        (const __attribute__((address_space(1))) unsigned int*)g,
        (__attribute__((address_space(3))) unsigned int*)l, 16, 0, 0);
}

// ---------------------------------------------------------------------------
// Kernel 2: block-sparse GEMM. A staged from padded xt via gll16 (r8's
// proven path); W converted IN-KERNEL from fp32 w (r10-proven pattern:
// reg-load + pack8 + swizzled ds_write) -> no wt buffer, no cross-kernel
// W dependency. fp16 MFMA, TM=256, wave 64x64 (4x4 rep), 2-phase dbuf,
// inline ballot-meta, phase-chunked XCD swizzle.
// ---------------------------------------------------------------------------
__global__ __launch_bounds__(256, 2)
void bsr_mfma8_kernel(const unsigned short* __restrict__ xt,
                      const float* __restrict__ w,
                      const float* __restrict__ bias,
                      const float* __restrict__ mask,
                      float* __restrict__ out) {
    __shared__ unsigned short xs[2][TM * BS];   // 2 x 32 KB
    __shared__ unsigned short wsb[2][BS * BS];  // 2 x  8 KB

    const int b     = blockIdx.x;
    const int xcd   = b & 7;
    const int j     = b >> 3;           // 0..255
    const int phase = j >> 7;           // 0..1
    const int idx   = j & 127;          // br-fast within phase
    const int br    = idx >> 1;
    const int mt    = xcd * 4 + phase * 2 + (idx & 1);

    const int tid  = threadIdx.x;
    const int lane = tid & 63;
    const int wv   = tid >> 6;          // wave 0..3 -> rows [wv*64, wv*64+64)
    const int fr   = lane & 15;
    const int kg   = lane >> 4;

    unsigned long long ball = mask_ballot(mask, br, lane);
    const int cnt = __popcll(ball);

    f32x4 acc[4][4];
#pragma unroll
    for (int a = 0; a < 4; ++a)
#pragma unroll
        for (int c = 0; c < 4; ++c) acc[a][c] = (f32x4)0.0f;

    const char* xbase = (const char*)xt;
    const int obase = br * BS;

    // ---- A: async gll16 from padded xt tiles (wave-contiguous 1KB) ----
    auto stageA = [&](int kb, int bb) {
        const char* xg = xbase + (size_t)(mt * 64 + kb) * XT_STRIDE_B;
        const int bx = wv * 8192;
#pragma unroll
        for (int q = 0; q < 8; ++q)
            gll16(xg + bx + q * 1024 + lane * 16, (char*)xs[bb] + bx + q * 1024);
    };
    // ---- W: reg-load fp32 (T14 issue-early), convert+ds_write late ----
    f32x4 rw[2][2];
    auto loadW = [&](int kb) {
#pragma unroll
        for (int l = 0; l < 2; ++l) {
            int g = tid + l * 256, row = g >> 3, slot = g & 7;
            const f32x4* src = (const f32x4*)(w + (size_t)(obase + row) * IN_F
                                              + kb * BS + slot * 8);
            rw[l][0] = src[0];
            rw[l][1] = src[1];
        }
    };
    auto commitW = [&](int bb) {
#pragma unroll
        for (int l = 0; l < 2; ++l) {
            int g = tid + l * 256, row = g >> 3, slot = g & 7;
            *(u16x8*)&wsb[bb][row * 64 + ((slot ^ (row & 7)) << 3)]
                = pack8(rw[l][0], rw[l][1]);
        }
    };

    unsigned long long rem = ball;
    int cur = 0;
    if (cnt > 0) {
        int kb0 = __ffsll(rem) - 1;
        rem &= rem - 1;
        loadW(kb0);
        stageA(kb0, 0);
        commitW(0);             // waits rw arrival (data dep)
    }
    __syncthreads();            // drains gll A; LDS visible

    for (int si = 0; si < cnt; ++si) {
        const bool more = (si + 1 < cnt);
        if (more) {                          // T14: issue early
            int kbn = __ffsll(rem) - 1;
            rem &= rem - 1;
            loadW(kbn);
            stageA(kbn, cur ^ 1);
        }

#pragma unroll
        for (int ks = 0; ks < 2; ++ks) {
            f16x8 a[4], bfr[4];
#pragma unroll
            for (int mr = 0; mr < 4; ++mr) {
                int row = wv * 64 + mr * 16 + fr;
                a[mr] = *(const f16x8*)&xs[cur][row * 64 + (((ks * 4 + kg) ^ (row & 7)) << 3)];
            }
#pragma unroll
            for (int nr = 0; nr < 4; ++nr) {
                int row = nr * 16 + fr;
                bfr[nr] = *(const f16x8*)&wsb[cur][row * 64 + (((ks * 4 + kg) ^ (row & 7)) << 3)];
            }
#pragma unroll
            for (int mr = 0; mr < 4; ++mr)
#pragma unroll
                for (int nr = 0; nr < 4; ++nr)
                    acc[mr][nr] = __builtin_amdgcn_mfma_f32_16x16x32_f16(
                        a[mr], bfr[nr], acc[mr][nr], 0, 0, 0);
        }
        if (more) commitW(cur ^ 1);          // T14: commit late (loads landed)
        __syncthreads();                     // all reads of cur done; next ready
        cur ^= 1;
    }

    // ---- epilogue: bias + fp32 stores. C/D: col=lane&15, row=(lane>>4)*4+r ----
    const int mbase = mt * TM;
#pragma unroll
    for (int nr = 0; nr < 4; ++nr) {
        float bv = bias[obase + nr * 16 + fr];
#pragma unroll
        for (int mr = 0; mr < 4; ++mr) {
#pragma unroll
            for (int r = 0; r < 4; ++r) {
                int m = mbase + wv * 64 + mr * 16 + kg * 4 + r;
                out[(size_t)m * OUT_F + obase + nr * 16 + fr] = acc[mr][nr][r] + bv;
            }
        }
    }
}

// ---------------------------------------------------------------------------
// Fallback (ws too small): fused in-loop conversion, single buffer.
// ---------------------------------------------------------------------------
__global__ __launch_bounds__(256, 3)
void bsr_fused_kernel(const float* __restrict__ x,
                      const float* __restrict__ w,
                      const float* __restrict__ bias,
                      const float* __restrict__ mask,
                      float* __restrict__ out) {
    __shared__ unsigned short xs[128 * BS];
    __shared__ unsigned short wsb[BS * BS];

    const int mt   = blockIdx.x;
    const int br   = blockIdx.y;
    const int tid  = threadIdx.x;
    const int lane = tid & 63;
    const int wv   = tid >> 6;
    const int fr   = lane & 15;
    const int kg   = lane >> 4;

    const int mbase = mt * 128;
    const int obase = br * BS;

    unsigned long long ball = mask_ballot(mask, br, lane);
    const int cnt = __popcll(ball);
    unsigned long long rem = ball;

    f32x4 acc[2][4];
#pragma unroll
    for (int a = 0; a < 2; ++a)
#pragma unroll
        for (int c = 0; c < 4; ++c) acc[a][c] = (f32x4)0.0f;

    for (int si = 0; si < cnt; ++si) {
        const int kb = __ffsll(rem) - 1;
        rem &= rem - 1;
        const int kbase = kb * BS;
#pragma unroll
        for (int l = 0; l < 4; ++l) {
            int g = tid + l * 256;
            int row = g >> 3, slot = g & 7;
            const f32x4* src = (const f32x4*)(x + (size_t)(mbase + row) * IN_F + kbase + slot * 8);
            *(u16x8*)&xs[row * BS + ((slot ^ (row & 7)) << 3)] = pack8(src[0], src[1]);
        }
#pragma unroll
        for (int l = 0; l < 2; ++l) {
            int g = tid + l * 256;
            int row = g >> 3, slot = g & 7;
            const f32x4* src = (const f32x4*)(w + (size_t)(obase + row) * IN_F + kbase + slot * 8);
            *(u16x8*)&wsb[row * BS + ((slot ^ (row & 7)) << 3)] = pack8(src[0], src[1]);
        }
        __syncthreads();
#pragma unroll
        for (int ks = 0; ks < 2; ++ks) {
            f16x8 a[2], bfr[4];
#pragma unroll
            for (int mr = 0; mr < 2; ++mr) {
                int row = wv * 32 + mr * 16 + fr;
                a[mr] = *(const f16x8*)&xs[row * BS + (((ks * 4 + kg) ^ (row & 7)) << 3)];
            }
#pragma unroll
            for (int nr = 0; nr < 4; ++nr) {
                int row = nr * 16 + fr;
                bfr[nr] = *(const f16x8*)&wsb[row * BS + (((ks * 4 + kg) ^ (row & 7)) << 3)];
            }
#pragma unroll
            for (int mr = 0; mr < 2; ++mr)
#pragma unroll
                for (int nr = 0; nr < 4; ++nr)
                    acc[mr][nr] = __builtin_amdgcn_mfma_f32_16x16x32_f16(
                        a[mr], bfr[nr], acc[mr][nr], 0, 0, 0);
        }
        __syncthreads();
    }

#pragma unroll
    for (int nr = 0; nr < 4; ++nr) {
        float bv = bias[obase + nr * 16 + fr];
#pragma unroll
        for (int mr = 0; mr < 2; ++mr) {
#pragma unroll
            for (int r = 0; r < 4; ++r) {
                int m = mbase + wv * 32 + mr * 16 + kg * 4 + r;
                out[(size_t)m * OUT_F + obase + nr * 16 + fr] = acc[mr][nr][r] + bv;
            }
        }
    }
}

extern "C" void kernel_launch(void* const* d_in, const int* in_sizes, int n_in,
                              void* d_out, int out_size, void* d_ws, size_t ws_size,
                              hipStream_t stream) {
    const float* x    = (const float*)d_in[0];
    const float* w    = (const float*)d_in[1];
    const float* bias = (const float*)d_in[2];
    const float* mask = (const float*)d_in[3];
    float* out = (float*)d_out;

    if (ws_size >= WS_NEEDED) {
        unsigned short* xt = (unsigned short*)((char*)d_ws + WS_XT_OFF);
        convert_x_kernel<<<1024, 256, 0, stream>>>(x, xt);
        bsr_mfma8_kernel<<<NMT * NB, 256, 0, stream>>>(xt, w, bias, mask, out);
    } else {
        dim3 grid(N_TOK / 128, NB);
        bsr_fused_kernel<<<grid, 256, 0, stream>>>(x, w, bias, mask, out);
    }
}

// Round 21
// 115.127 us; speedup vs baseline: 1.2106x; 1.2106x over previous
//
#include <hip/hip_runtime.h>
#include <hip/hip_fp16.h>
#include <cstdint>

#define IN_F   4096
#define OUT_F  4096
#define BS     64      // sparsity block size
#define NB     64      // blocks per weight dim
#define N_TOK  8192
#define TM     256     // token tile per workgroup (4 waves x 64 rows)
#define NMT    (N_TOK / TM)   // 32 token tiles

typedef __attribute__((ext_vector_type(8))) _Float16       f16x8;
typedef __attribute__((ext_vector_type(8))) unsigned short u16x8;
typedef __attribute__((ext_vector_type(4))) float          f32x4;

// wave-uniform ballot of the block-constant mask row `br`
__device__ __forceinline__ unsigned long long mask_ballot(
        const float* __restrict__ mask, int br, int lane) {
    float mv = mask[(size_t)(br * BS) * IN_F + (size_t)lane * BS];
    return __ballot(mv != 0.0f);
}

// pack 8 fp32 -> 8 fp16 (RNE) bit patterns
__device__ __forceinline__ u16x8 pack8(f32x4 a, f32x4 b) {
    u16x8 o;
#pragma unroll
    for (int j = 0; j < 4; ++j) o[j]     = __half_as_ushort(__float2half_rn(a[j]));
#pragma unroll
    for (int j = 0; j < 4; ++j) o[4 + j] = __half_as_ushort(__float2half_rn(b[j]));
    return o;
}

// ---------------------------------------------------------------------------
// Single fused block-sparse GEMM: out = x @ (W o mask)^T + bias.
// fp16 MFMA, fp32 accumulate. NO precompute, NO workspace: both A (x) and
// B (W) are reg-loaded as fp32, converted to fp16, and ds_written into
// XOR-swizzled LDS tiles inside the K-loop (r10-fallback pattern, proven
// in r20 for W at ~45us GEMM; extended to A here). T14: loads for si+1
// issued before compute(si), converts+ds_writes committed after.
//
// XCD 1-mt phases: the 64 co-resident WGs of (xcd, phase) share ONE mt's
// 4 MB fp32 x-slab = exactly one XCD L2 -> x HBM traffic ~134 MB compulsory.
// W unique kept blocks = 6.7 MB -> L3-resident across re-reads.
// This deletes the 90us standalone transpose (r20) and the 134 MB xt
// round-trip entirely.
// ---------------------------------------------------------------------------
__global__ __launch_bounds__(256, 2)
void bsr_fused4_kernel(const float* __restrict__ x,
                       const float* __restrict__ w,
                       const float* __restrict__ bias,
                       const float* __restrict__ mask,
                       float* __restrict__ out) {
    __shared__ unsigned short xs[2][TM * BS];   // 2 x 32 KB fp16 A tile
    __shared__ unsigned short wsb[2][BS * BS];  // 2 x  8 KB fp16 W tile

    const int b     = blockIdx.x;     // 0..2047
    const int xcd   = b & 7;
    const int j     = b >> 3;         // 0..255
    const int phase = j >> 6;         // 0..3  (1-mt phase: 4MB fp32 slab = L2)
    const int br    = j & 63;         // br-fast within phase
    const int mt    = xcd * 4 + phase;

    const int tid  = threadIdx.x;
    const int lane = tid & 63;
    const int wv   = tid >> 6;        // wave 0..3 -> rows [wv*64, wv*64+64)
    const int fr   = lane & 15;
    const int kg   = lane >> 4;

    const int mbase = mt * TM;
    const int obase = br * BS;

    unsigned long long ball = mask_ballot(mask, br, lane);
    const int cnt = __popcll(ball);

    f32x4 acc[4][4];
#pragma unroll
    for (int a = 0; a < 4; ++a)
#pragma unroll
        for (int c = 0; c < 4; ++c) acc[a][c] = (f32x4)0.0f;

    // ---- A: reg-load fp32 x tile (256x64), convert+swizzled ds_write ----
    // thread covers 8 (row, slot8) pairs: g = tid + l*256, row = g>>3,
    // slot = g&7. Wave instruction touches 8 rows x 256B contiguous.
    f32x4 rA[8][2];
    auto loadA = [&](int kb) {
#pragma unroll
        for (int l = 0; l < 8; ++l) {
            int g = tid + l * 256, row = g >> 3, slot = g & 7;
            const f32x4* src = (const f32x4*)(x + (size_t)(mbase + row) * IN_F
                                              + kb * BS + slot * 8);
            rA[l][0] = src[0];
            rA[l][1] = src[1];
        }
    };
    auto commitA = [&](int bb) {
#pragma unroll
        for (int l = 0; l < 8; ++l) {
            int g = tid + l * 256, row = g >> 3, slot = g & 7;
            *(u16x8*)&xs[bb][row * 64 + ((slot ^ (row & 7)) << 3)]
                = pack8(rA[l][0], rA[l][1]);
        }
    };
    // ---- W: reg-load fp32 (64x64), convert+swizzled ds_write (r20-proven) ----
    f32x4 rW[2][2];
    auto loadW = [&](int kb) {
#pragma unroll
        for (int l = 0; l < 2; ++l) {
            int g = tid + l * 256, row = g >> 3, slot = g & 7;
            const f32x4* src = (const f32x4*)(w + (size_t)(obase + row) * IN_F
                                              + kb * BS + slot * 8);
            rW[l][0] = src[0];
            rW[l][1] = src[1];
        }
    };
    auto commitW = [&](int bb) {
#pragma unroll
        for (int l = 0; l < 2; ++l) {
            int g = tid + l * 256, row = g >> 3, slot = g & 7;
            *(u16x8*)&wsb[bb][row * 64 + ((slot ^ (row & 7)) << 3)]
                = pack8(rW[l][0], rW[l][1]);
        }
    };

    unsigned long long rem = ball;
    int cur = 0;
    if (cnt > 0) {
        int kb0 = __ffsll(rem) - 1;
        rem &= rem - 1;
        loadA(kb0);
        loadW(kb0);
        commitA(0);             // waits its loads via data dep
        commitW(0);
    }
    __syncthreads();

    for (int si = 0; si < cnt; ++si) {
        const bool more = (si + 1 < cnt);
        if (more) {                          // T14: issue next-tile loads early
            int kbn = __ffsll(rem) - 1;
            rem &= rem - 1;
            loadA(kbn);
            loadW(kbn);
        }

#pragma unroll
        for (int ks = 0; ks < 2; ++ks) {
            f16x8 a[4], bfr[4];
#pragma unroll
            for (int mr = 0; mr < 4; ++mr) {
                int row = wv * 64 + mr * 16 + fr;
                a[mr] = *(const f16x8*)&xs[cur][row * 64 + (((ks * 4 + kg) ^ (row & 7)) << 3)];
            }
#pragma unroll
            for (int nr = 0; nr < 4; ++nr) {
                int row = nr * 16 + fr;
                bfr[nr] = *(const f16x8*)&wsb[cur][row * 64 + (((ks * 4 + kg) ^ (row & 7)) << 3)];
            }
#pragma unroll
            for (int mr = 0; mr < 4; ++mr)
#pragma unroll
                for (int nr = 0; nr < 4; ++nr)
                    acc[mr][nr] = __builtin_amdgcn_mfma_f32_16x16x32_f16(
                        a[mr], bfr[nr], acc[mr][nr], 0, 0, 0);
        }
        if (more) {                          // T14: commit late (loads landed)
            commitA(cur ^ 1);
            commitW(cur ^ 1);
        }
        __syncthreads();                     // all reads of cur done; next ready
        cur ^= 1;
    }

    // ---- epilogue: bias + fp32 stores. C/D: col=lane&15, row=(lane>>4)*4+r ----
#pragma unroll
    for (int nr = 0; nr < 4; ++nr) {
        float bv = bias[obase + nr * 16 + fr];
#pragma unroll
        for (int mr = 0; mr < 4; ++mr) {
#pragma unroll
            for (int r = 0; r < 4; ++r) {
                int m = mbase + wv * 64 + mr * 16 + kg * 4 + r;
                out[(size_t)m * OUT_F + obase + nr * 16 + fr] = acc[mr][nr][r] + bv;
            }
        }
    }
}

extern "C" void kernel_launch(void* const* d_in, const int* in_sizes, int n_in,
                              void* d_out, int out_size, void* d_ws, size_t ws_size,
                              hipStream_t stream) {
    const float* x    = (const float*)d_in[0];
    const float* w    = (const float*)d_in[1];
    const float* bias = (const float*)d_in[2];
    const float* mask = (const float*)d_in[3];
    float* out = (float*)d_out;

    bsr_fused4_kernel<<<NMT * NB, 256, 0, stream>>>(x, w, bias, mask, out);
}